// Round 14
// baseline (159.629 us; speedup 1.0000x reference)
//
#include <hip/hip_runtime.h>
#include <hip/hip_bf16.h>
#include <hip/hip_fp16.h>
#include <math.h>

#define N_NODES 10000
#define N_EDGES 320000
#define IN_SIZE 256
#define H1 8
#define D1 64
#define F1 512
#define H2 1
#define D2 64
#define F2 64

using f16x8 = __attribute__((ext_vector_type(8))) _Float16;
using f32x4 = __attribute__((ext_vector_type(4))) float;

// ---- fused prep: x->f16, W1^T->f16, W2^T->f16, dst histogram (8 sub-counters) ----
#define PREP_X (N_NODES * IN_SIZE / 4)
#define PREP_W1 (IN_SIZE * F1)
#define PREP_W2 (F1 * F2)
__global__ void prep_kernel(const float* __restrict__ x, __half* __restrict__ xh,
                            const float* __restrict__ W1, __half* __restrict__ W1T,
                            const float* __restrict__ W2, __half* __restrict__ W2T,
                            const int* __restrict__ dst, int* __restrict__ counts8) {
  int i = blockIdx.x * blockDim.x + threadIdx.x;
  if (i < PREP_X) {
    float4 v = reinterpret_cast<const float4*>(x)[i];
    reinterpret_cast<__half2*>(xh)[i * 2 + 0] = __floats2half2_rn(v.x, v.y);
    reinterpret_cast<__half2*>(xh)[i * 2 + 1] = __floats2half2_rn(v.z, v.w);
    return;
  }
  i -= PREP_X;
  if (i < PREP_W1) {
    int k = i / F1, n = i % F1;
    W1T[(size_t)n * IN_SIZE + k] = __float2half(W1[i]);
    return;
  }
  i -= PREP_W1;
  if (i < PREP_W2) {
    int k = i / F2, n = i % F2;
    W2T[(size_t)n * F1 + k] = __float2half(W2[i]);
    return;
  }
  i -= PREP_W2;
  if (i < N_EDGES) atomicAdd(&counts8[dst[i] * 8 + (i & 7)], 1);
}

// ---- scan: row_off + 8 sub-cursors + degree counting-sort (desc) ----
__global__ __launch_bounds__(1024) void scan_kernel(const int* __restrict__ counts8,
                                                    int* __restrict__ row_off,
                                                    int* __restrict__ cursor8,
                                                    int* __restrict__ nord, int N) {
  __shared__ int part[1024];
  __shared__ int bins[129];
  __shared__ int bcur[129];
  int tid = threadIdx.x;
  int T = blockDim.x;
  int chunk = (N + T - 1) / T;
  int beg = tid * chunk;
  int end = min(beg + chunk, N);
  int s = 0;
  for (int i = beg; i < end; ++i) {
    int d = 0;
#pragma unroll
    for (int j = 0; j < 8; ++j) d += counts8[i * 8 + j];
    s += d;
  }
  part[tid] = s;
  if (tid < 129) bins[tid] = 0;
  __syncthreads();
  for (int off = 1; off < T; off <<= 1) {
    int v = (tid >= off) ? part[tid - off] : 0;
    __syncthreads();
    part[tid] += v;
    __syncthreads();
  }
  int run = (tid > 0) ? part[tid - 1] : 0;
  for (int i = beg; i < end; ++i) {
    row_off[i] = run;
    int acc = run, deg = 0;
#pragma unroll
    for (int j = 0; j < 8; ++j) {
      int c = counts8[i * 8 + j];
      cursor8[i * 8 + j] = acc;
      acc += c;
      deg += c;
    }
    run += deg;
    atomicAdd(&bins[min(deg, 128)], 1);
  }
  if (tid == T - 1) row_off[N] = run;
  __syncthreads();
  if (tid == 0) {
    int r = 0;
    for (int d = 128; d >= 0; --d) { bcur[d] = r; r += bins[d]; }
  }
  __syncthreads();
  for (int i = beg; i < end; ++i) {
    int deg = 0;
#pragma unroll
    for (int j = 0; j < 8; ++j) deg += counts8[i * 8 + j];
    nord[atomicAdd(&bcur[min(deg, 128)], 1)] = i;
  }
}

// ---- shared LDS-staged MFMA GEMM tile (64 rows x 64 cols per block) ----
template <int KSTEPS>
__device__ __forceinline__ void gemm_tile(
    int rowBase, int colBase, const __half* __restrict__ A,
    const __half* __restrict__ BT, __half* __restrict__ Ch,
    const float* __restrict__ al, const float* __restrict__ ar,
    float* __restrict__ el, float* __restrict__ er,
    int M, int Ncols, int H, f16x8* Bs) {
  constexpr int K = KSTEPS * 32;
  constexpr int UPC = 4 * KSTEPS;  // 16B units per column
  int tid = threadIdx.x;
  for (int u = tid; u < 64 * UPC; u += 256) {
    int col = u / UPC;
    int off = u % UPC;
    f16x8 v = *reinterpret_cast<const f16x8*>(BT + (size_t)(colBase + col) * K + off * 8);
    Bs[u ^ (col & 7)] = v;
  }
  __syncthreads();
  int w = tid >> 6, lane = tid & 63;
  int r16 = lane & 15, ko = lane >> 4;
  int rb = rowBase + w * 16;
  int arow = rb + r16;
  if (arow >= M) arow = M - 1;
  const f16x8* Ap = reinterpret_cast<const f16x8*>(A + (size_t)arow * K + ko * 8);
  f32x4 acc[4] = {};
#pragma unroll
  for (int kk = 0; kk < KSTEPS; ++kk) {
    f16x8 af = Ap[kk * 4];
#pragma unroll
    for (int c = 0; c < 4; ++c) {
      int col = c * 16 + r16;
      f16x8 bf = Bs[(col * UPC + kk * 4 + ko) ^ (col & 7)];
      acc[c] = __builtin_amdgcn_mfma_f32_16x16x32_f16(af, bf, acc[c], 0, 0, 0);
    }
  }
  int h = colBase >> 6;
  float alv[4], arv[4];
#pragma unroll
  for (int c = 0; c < 4; ++c) {
    alv[c] = al[colBase + c * 16 + r16];
    arv[c] = ar[colBase + c * 16 + r16];
  }
#pragma unroll
  for (int r = 0; r < 4; ++r) {
    int row = rb + (lane >> 4) * 4 + r;
    bool ok = row < M;
    float pl = 0.f, pr = 0.f;
#pragma unroll
    for (int c = 0; c < 4; ++c) {
      float v = acc[c][r];
      if (ok) Ch[(size_t)row * Ncols + colBase + c * 16 + r16] = __float2half(v);
      pl += v * alv[c];
      pr += v * arv[c];
    }
#pragma unroll
    for (int o = 8; o > 0; o >>= 1) {
      pl += __shfl_xor(pl, o);
      pr += __shfl_xor(pr, o);
    }
    if (r16 == 0 && ok) {
      el[(size_t)row * H + h] = pl;
      er[(size_t)row * H + h] = pr;
    }
  }
}

// ---- merged dispatch: CSR scatter blocks FIRST, then GEMM1 tiles ----
// Scatter is latency/atomic-bound; placing it first lets it overlap with the
// MFMA-bound gemm blocks instead of queueing behind them.
#define GEMM1_RB ((N_NODES + 63) / 64)
#define GEMM1_BLOCKS (8 * GEMM1_RB)
#define SCAT_BLOCKS ((N_EDGES + 255) / 256)
__global__ __launch_bounds__(256) void gemm1_scatter_kernel(
    const __half* __restrict__ A, const __half* __restrict__ BT,
    __half* __restrict__ Ch, const float* __restrict__ al,
    const float* __restrict__ ar, float* __restrict__ el,
    float* __restrict__ er,
    const int* __restrict__ src, const int* __restrict__ dst,
    int* __restrict__ cursor8, int* __restrict__ src_csr) {
  __shared__ f16x8 Bs[256 * 8];  // 32 KB (KSTEPS=8)
  if (blockIdx.x < SCAT_BLOCKS) {
    int e = blockIdx.x * 256 + threadIdx.x;
    if (e < N_EDGES) {
      int p = atomicAdd(&cursor8[dst[e] * 8 + (e & 7)], 1);
      src_csr[p] = src[e];
    }
    return;
  }
  int bid = blockIdx.x - SCAT_BLOCKS;
  gemm_tile<IN_SIZE / 32>((bid >> 3) * 64, (bid & 7) * 64,
                          A, BT, Ch, al, ar, el, er, N_NODES, F1, H1, Bs);
}

// ---- layer-2 GEMM: one wave per block, 16 rows x 64 cols, no LDS ----
// W2T (64 KB) is L2-resident; 625 small blocks give ~2.4 blocks/CU of TLP
// instead of 157 fat blocks at <1/CU.
__global__ __launch_bounds__(64) void gemm2_kernel(
    const __half* __restrict__ A, const __half* __restrict__ BT,
    __half* __restrict__ Ch, const float* __restrict__ al,
    const float* __restrict__ ar, float* __restrict__ el,
    float* __restrict__ er) {
  constexpr int K = F1;
  constexpr int KSTEPS = F1 / 32;
  int lane = threadIdx.x & 63;
  int rowBase = blockIdx.x * 16;
  int r16 = lane & 15, ko = lane >> 4;
  int arow = rowBase + r16;
  if (arow >= N_NODES) arow = N_NODES - 1;
  const f16x8* Ap = reinterpret_cast<const f16x8*>(A + (size_t)arow * K + ko * 8);
  const __half* Bbase = BT + ko * 8;
  f32x4 acc[4] = {};
#pragma unroll
  for (int kk = 0; kk < KSTEPS; ++kk) {
    f16x8 af = Ap[kk * 4];
#pragma unroll
    for (int c = 0; c < 4; ++c) {
      f16x8 bf = *reinterpret_cast<const f16x8*>(
          Bbase + (size_t)(c * 16 + r16) * K + kk * 32);
      acc[c] = __builtin_amdgcn_mfma_f32_16x16x32_f16(af, bf, acc[c], 0, 0, 0);
    }
  }
  float alv[4], arv[4];
#pragma unroll
  for (int c = 0; c < 4; ++c) {
    alv[c] = al[c * 16 + r16];
    arv[c] = ar[c * 16 + r16];
  }
#pragma unroll
  for (int r = 0; r < 4; ++r) {
    int row = rowBase + ko * 4 + r;
    bool ok = row < N_NODES;
    float pl = 0.f, pr = 0.f;
#pragma unroll
    for (int c = 0; c < 4; ++c) {
      float v = acc[c][r];
      if (ok) Ch[(size_t)row * F2 + c * 16 + r16] = __float2half(v);
      pl += v * alv[c];
      pr += v * arv[c];
    }
#pragma unroll
    for (int o = 8; o > 0; o >>= 1) {
      pl += __shfl_xor(pl, o);
      pr += __shfl_xor(pr, o);
    }
    if (r16 == 0 && ok) {
      el[row] = pl;
      er[row] = pr;
    }
  }
}

__device__ __forceinline__ float leaky_exp(float v) {
  v = (v >= 0.f) ? v : 0.2f * v;
  return __expf(fminf(v, 80.f));
}

// ---- aggregation layer 1 (exp fused): block = node, wave = 128-ch tile ----
__global__ __launch_bounds__(256) void agg1_kernel(
    const int* __restrict__ row_off, const int* __restrict__ src_csr,
    const float* __restrict__ el, const float* __restrict__ er,
    const __half* __restrict__ fth, const float* __restrict__ bias,
    __half* __restrict__ out, const int* __restrict__ nord) {
  int t = threadIdx.x;
  int w = t >> 6, lane = t & 63;
  int n = nord[blockIdx.x];
  int e = lane >> 4;
  int sub = lane & 15;
  int chb = w * 128 + sub * 8;
  int h = chb >> 6;
  int beg = row_off[n], end = row_off[n + 1];
  float er_h = er[n * 8 + h];
  float s_run = 0.f;
  float acc[8] = {0.f, 0.f, 0.f, 0.f, 0.f, 0.f, 0.f, 0.f};
  if (beg < end) {
    int iA = min(beg + e, end - 1);
    bool okA = (beg + e) < end;
    int sA = src_csr[iA];
    int iB = min(beg + 4 + e, end - 1);
    bool okB = (beg + 4 + e) < end;
    int sB = src_csr[iB];
    float elA = el[sA * 8 + h];
    uint4 ftA = *reinterpret_cast<const uint4*>(fth + (size_t)sA * F1 + chb);
    for (int c = beg; c < end; c += 4) {
      int iC = min(c + 8 + e, end - 1);
      bool okC = (c + 8 + e) < end;
      int sC = src_csr[iC];
      float elB = el[sB * 8 + h];
      uint4 ftB = *reinterpret_cast<const uint4*>(fth + (size_t)sB * F1 + chb);
      float ex = okA ? leaky_exp(elA + er_h) : 0.f;
      float2 f0 = __half22float2(*reinterpret_cast<const __half2*>(&ftA.x));
      float2 f1 = __half22float2(*reinterpret_cast<const __half2*>(&ftA.y));
      float2 f2 = __half22float2(*reinterpret_cast<const __half2*>(&ftA.z));
      float2 f3 = __half22float2(*reinterpret_cast<const __half2*>(&ftA.w));
      acc[0] += ex * f0.x; acc[1] += ex * f0.y;
      acc[2] += ex * f1.x; acc[3] += ex * f1.y;
      acc[4] += ex * f2.x; acc[5] += ex * f2.y;
      acc[6] += ex * f3.x; acc[7] += ex * f3.y;
      s_run += ex;
      sA = sB; okA = okB; elA = elB; ftA = ftB;
      sB = sC; okB = okC;
    }
  }
#pragma unroll
  for (int i = 0; i < 8; ++i) {
    acc[i] += __shfl_xor(acc[i], 16);
    acc[i] += __shfl_xor(acc[i], 32);
  }
  s_run += __shfl_xor(s_run, 16);
  s_run += __shfl_xor(s_run, 32);
  if (e == 0) {
    float inv = (s_run > 0.f) ? (1.f / s_run) : 0.f;
    uint4 pack;
    __half2* ph = reinterpret_cast<__half2*>(&pack);
#pragma unroll
    for (int i = 0; i < 4; ++i) {
      float v0 = acc[2 * i + 0] * inv + bias[chb + 2 * i + 0];
      float v1 = acc[2 * i + 1] * inv + bias[chb + 2 * i + 1];
      v0 = (v0 > 0.f) ? v0 : (__expf(v0) - 1.f);  // ELU
      v1 = (v1 > 0.f) ? v1 : (__expf(v1) - 1.f);
      ph[i] = __floats2half2_rn(v0, v1);
    }
    *reinterpret_cast<uint4*>(out + (size_t)n * F1 + chb) = pack;
  }
}

// ---- aggregation layer 2 (H=1, exp fused): wave per node ----
template <int NPB>
__global__ __launch_bounds__(NPB * 64) void agg2_kernel(
    const int* __restrict__ row_off, const int* __restrict__ src_csr,
    const float* __restrict__ el, const float* __restrict__ er,
    const __half* __restrict__ fth, const float* __restrict__ bias,
    float* __restrict__ out, const int* __restrict__ nord) {
  int t = threadIdx.x;
  int w = t >> 6, lane = t & 63;
  int n = nord[blockIdx.x * NPB + w];
  int e = lane >> 3;
  int q = lane & 7;
  int chb = q * 8;
  int beg = row_off[n], end = row_off[n + 1];
  float er_n = er[n];
  float s_run = 0.f;
  float acc[8] = {0.f, 0.f, 0.f, 0.f, 0.f, 0.f, 0.f, 0.f};
  if (beg < end) {
    int iA = min(beg + e, end - 1);
    bool okA = (beg + e) < end;
    int sA = src_csr[iA];
    int iB = min(beg + 8 + e, end - 1);
    bool okB = (beg + 8 + e) < end;
    int sB = src_csr[iB];
    float elA = el[sA];
    uint4 ftA = *reinterpret_cast<const uint4*>(fth + (size_t)sA * F2 + chb);
    for (int c = beg; c < end; c += 8) {
      int iC = min(c + 16 + e, end - 1);
      bool okC = (c + 16 + e) < end;
      int sC = src_csr[iC];
      float elB = el[sB];
      uint4 ftB = *reinterpret_cast<const uint4*>(fth + (size_t)sB * F2 + chb);
      float ex = okA ? leaky_exp(elA + er_n) : 0.f;
      float2 f0 = __half22float2(*reinterpret_cast<const __half2*>(&ftA.x));
      float2 f1 = __half22float2(*reinterpret_cast<const __half2*>(&ftA.y));
      float2 f2 = __half22float2(*reinterpret_cast<const __half2*>(&ftA.z));
      float2 f3 = __half22float2(*reinterpret_cast<const __half2*>(&ftA.w));
      acc[0] += ex * f0.x; acc[1] += ex * f0.y;
      acc[2] += ex * f1.x; acc[3] += ex * f1.y;
      acc[4] += ex * f2.x; acc[5] += ex * f2.y;
      acc[6] += ex * f3.x; acc[7] += ex * f3.y;
      s_run += ex;
      sA = sB; okA = okB; elA = elB; ftA = ftB;
      sB = sC; okB = okC;
    }
  }
#pragma unroll
  for (int i = 0; i < 8; ++i) {
    acc[i] += __shfl_xor(acc[i], 8);
    acc[i] += __shfl_xor(acc[i], 16);
    acc[i] += __shfl_xor(acc[i], 32);
  }
  s_run += __shfl_xor(s_run, 8);
  s_run += __shfl_xor(s_run, 16);
  s_run += __shfl_xor(s_run, 32);
  if (e == 0) {
    float inv = (s_run > 0.f) ? (1.f / s_run) : 0.f;
    float o[8];
#pragma unroll
    for (int i = 0; i < 8; ++i) o[i] = acc[i] * inv + bias[chb + i];
    float* op = &out[(size_t)n * F2 + chb];
    *reinterpret_cast<float4*>(op) = make_float4(o[0], o[1], o[2], o[3]);
    *reinterpret_cast<float4*>(op + 4) = make_float4(o[4], o[5], o[6], o[7]);
  }
}

extern "C" void kernel_launch(void* const* d_in, const int* in_sizes, int n_in,
                              void* d_out, int out_size, void* d_ws, size_t ws_size,
                              hipStream_t stream) {
  const float* x   = (const float*)d_in[0];
  const int*   src = (const int*)d_in[1];
  const int*   dst = (const int*)d_in[2];
  const float* W1  = (const float*)d_in[3];
  const float* al1 = (const float*)d_in[4];
  const float* ar1 = (const float*)d_in[5];
  const float* b1  = (const float*)d_in[6];
  const float* W2  = (const float*)d_in[7];
  const float* al2 = (const float*)d_in[8];
  const float* ar2 = (const float*)d_in[9];
  const float* b2  = (const float*)d_in[10];
  float* out = (float*)d_out;

  char* ws = (char*)d_ws;
  size_t off = 0;
  auto alloc = [&](size_t bytes) -> void* {
    void* p = ws + off;
    off += (bytes + 255) & ~(size_t)255;
    return p;
  };
  size_t zbeg = off;
  int* counts8 = (int*)alloc((size_t)N_NODES * 8 * 4);
  size_t zend = off;
  int* cursor8 = (int*)alloc((size_t)N_NODES * 8 * 4);
  int* nord    = (int*)alloc((size_t)N_NODES * 4);
  __half* xh   = (__half*)alloc((size_t)N_NODES * IN_SIZE * 2);
  __half* W1T  = (__half*)alloc((size_t)IN_SIZE * F1 * 2);
  __half* W2T  = (__half*)alloc((size_t)F1 * F2 * 2);
  __half* ft1h = (__half*)alloc((size_t)N_NODES * F1 * 2);
  __half* h1h  = (__half*)alloc((size_t)N_NODES * F1 * 2);
  __half* ft2h = (__half*)alloc((size_t)N_NODES * F2 * 2);
  float* el1 = (float*)alloc((size_t)N_NODES * H1 * 4);
  float* er1 = (float*)alloc((size_t)N_NODES * H1 * 4);
  float* el2 = (float*)alloc((size_t)N_NODES * 4);
  float* er2 = (float*)alloc((size_t)N_NODES * 4);
  int* row_off = (int*)alloc((size_t)(N_NODES + 1) * 4);
  int* src_csr = (int*)alloc((size_t)N_EDGES * 4);
  (void)ws_size; (void)in_sizes; (void)n_in; (void)out_size;

  hipMemsetAsync(ws + zbeg, 0, zend - zbeg, stream);

  dim3 b256(256);
  int prep_total = PREP_X + PREP_W1 + PREP_W2 + N_EDGES;

  // prep (x cvt + W transposes + dst histogram), scan(+sub-cursors, sort)
  prep_kernel<<<(prep_total + 255) / 256, b256, 0, stream>>>(
      x, xh, W1, W1T, W2, W2T, dst, counts8);
  scan_kernel<<<1, 1024, 0, stream>>>(counts8, row_off, cursor8, nord, N_NODES);

  // ---- layer 1: scatter + GEMM1 merged (scatter blocks first) ----
  gemm1_scatter_kernel<<<SCAT_BLOCKS + GEMM1_BLOCKS, b256, 0, stream>>>(
      xh, W1T, ft1h, al1, ar1, el1, er1, src, dst, cursor8, src_csr);
  agg1_kernel<<<N_NODES, b256, 0, stream>>>(
      row_off, src_csr, el1, er1, ft1h, b1, h1h, nord);

  // ---- layer 2 ----
  gemm2_kernel<<<(N_NODES + 15) / 16, 64, 0, stream>>>(
      h1h, W2T, ft2h, al2, ar2, el2, er2);
  agg2_kernel<4><<<N_NODES / 4, b256, 0, stream>>>(
      row_off, src_csr, el2, er2, ft2h, b2, out, nord);
}

// Round 15
// 156.549 us; speedup vs baseline: 1.0197x; 1.0197x over previous
//
#include <hip/hip_runtime.h>
#include <hip/hip_bf16.h>
#include <hip/hip_fp16.h>
#include <math.h>

#define N_NODES 10000
#define N_EDGES 320000
#define IN_SIZE 256
#define H1 8
#define D1 64
#define F1 512
#define H2 1
#define D2 64
#define F2 64

using f16x8 = __attribute__((ext_vector_type(8))) _Float16;
using f32x4 = __attribute__((ext_vector_type(4))) float;

// ---- fused prep: x->f16, W1^T->f16, W2^T->f16, dst histogram (8 sub-counters) ----
#define PREP_X (N_NODES * IN_SIZE / 4)
#define PREP_W1 (IN_SIZE * F1)
#define PREP_W2 (F1 * F2)
__global__ void prep_kernel(const float* __restrict__ x, __half* __restrict__ xh,
                            const float* __restrict__ W1, __half* __restrict__ W1T,
                            const float* __restrict__ W2, __half* __restrict__ W2T,
                            const int* __restrict__ dst, int* __restrict__ counts8) {
  int i = blockIdx.x * blockDim.x + threadIdx.x;
  if (i < PREP_X) {
    float4 v = reinterpret_cast<const float4*>(x)[i];
    reinterpret_cast<__half2*>(xh)[i * 2 + 0] = __floats2half2_rn(v.x, v.y);
    reinterpret_cast<__half2*>(xh)[i * 2 + 1] = __floats2half2_rn(v.z, v.w);
    return;
  }
  i -= PREP_X;
  if (i < PREP_W1) {
    int k = i / F1, n = i % F1;
    W1T[(size_t)n * IN_SIZE + k] = __float2half(W1[i]);
    return;
  }
  i -= PREP_W1;
  if (i < PREP_W2) {
    int k = i / F2, n = i % F2;
    W2T[(size_t)n * F1 + k] = __float2half(W2[i]);
    return;
  }
  i -= PREP_W2;
  if (i < N_EDGES) atomicAdd(&counts8[dst[i] * 8 + (i & 7)], 1);
}

// ---- parallel CSR-prep scan, stage 1: per-node degree + bins + block sums ----
#define NSCAN_BLOCKS ((N_NODES + 255) / 256)
__global__ __launch_bounds__(256) void deg_kernel(const int* __restrict__ counts8,
                                                  int* __restrict__ deg,
                                                  int* __restrict__ dbins,
                                                  int* __restrict__ bsum) {
  __shared__ int red[256];
  int tid = threadIdx.x;
  int i = blockIdx.x * 256 + tid;
  int d = 0;
  if (i < N_NODES) {
#pragma unroll
    for (int j = 0; j < 8; ++j) d += counts8[i * 8 + j];
    deg[i] = d;
    atomicAdd(&dbins[min(d, 128)], 1);
  }
  red[tid] = d;
  __syncthreads();
  for (int o = 128; o > 0; o >>= 1) {
    if (tid < o) red[tid] += red[tid + o];
    __syncthreads();
  }
  if (tid == 0) bsum[blockIdx.x] = red[0];
}

// ---- stage 2: tiny serial scans (LDS-staged), 1 block ----
__global__ __launch_bounds__(256) void scan_small_kernel(const int* __restrict__ bsum,
                                                         const int* __restrict__ dbins,
                                                         int* __restrict__ bbase,
                                                         int* __restrict__ dcur,
                                                         int* __restrict__ row_off) {
  __shared__ int lb[NSCAN_BLOCKS];
  __shared__ int ld[129];
  int tid = threadIdx.x;
  if (tid < NSCAN_BLOCKS) lb[tid] = bsum[tid];
  if (tid < 129) ld[tid] = dbins[tid];
  __syncthreads();
  if (tid == 0) {
    int run = 0;
    for (int b = 0; b < NSCAN_BLOCKS; ++b) { int c = lb[b]; lb[b] = run; run += c; }
    row_off[N_NODES] = run;
    int r = 0;
    for (int d = 128; d >= 0; --d) { int c = ld[d]; ld[d] = r; r += c; }
  }
  __syncthreads();
  if (tid < NSCAN_BLOCKS) bbase[tid] = lb[tid];
  if (tid < 129) dcur[tid] = ld[tid];
}

// ---- stage 3: per-block prefix scan -> row_off, cursor8, nord ----
__global__ __launch_bounds__(256) void finalize_kernel(const int* __restrict__ counts8,
                                                       const int* __restrict__ deg,
                                                       const int* __restrict__ bbase,
                                                       int* __restrict__ row_off,
                                                       int* __restrict__ cursor8,
                                                       int* __restrict__ dcur,
                                                       int* __restrict__ nord) {
  __shared__ int pre[256];
  int tid = threadIdx.x;
  int i = blockIdx.x * 256 + tid;
  int d = (i < N_NODES) ? deg[i] : 0;
  pre[tid] = d;
  __syncthreads();
  for (int o = 1; o < 256; o <<= 1) {
    int v = (tid >= o) ? pre[tid - o] : 0;
    __syncthreads();
    pre[tid] += v;
    __syncthreads();
  }
  if (i < N_NODES) {
    int base = bbase[blockIdx.x] + pre[tid] - d;  // exclusive prefix
    row_off[i] = base;
    int acc = base;
#pragma unroll
    for (int j = 0; j < 8; ++j) {
      cursor8[i * 8 + j] = acc;
      acc += counts8[i * 8 + j];
    }
    int pos = atomicAdd(&dcur[min(d, 128)], 1);
    nord[pos] = i;
  }
}

// ---- shared LDS-staged MFMA GEMM tile (64 rows x 64 cols per block) ----
template <int KSTEPS>
__device__ __forceinline__ void gemm_tile(
    int rowBase, int colBase, const __half* __restrict__ A,
    const __half* __restrict__ BT, __half* __restrict__ Ch,
    const float* __restrict__ al, const float* __restrict__ ar,
    float* __restrict__ el, float* __restrict__ er,
    int M, int Ncols, int H, f16x8* Bs) {
  constexpr int K = KSTEPS * 32;
  constexpr int UPC = 4 * KSTEPS;  // 16B units per column
  int tid = threadIdx.x;
  for (int u = tid; u < 64 * UPC; u += 256) {
    int col = u / UPC;
    int off = u % UPC;
    f16x8 v = *reinterpret_cast<const f16x8*>(BT + (size_t)(colBase + col) * K + off * 8);
    Bs[u ^ (col & 7)] = v;
  }
  __syncthreads();
  int w = tid >> 6, lane = tid & 63;
  int r16 = lane & 15, ko = lane >> 4;
  int rb = rowBase + w * 16;
  int arow = rb + r16;
  if (arow >= M) arow = M - 1;
  const f16x8* Ap = reinterpret_cast<const f16x8*>(A + (size_t)arow * K + ko * 8);
  f32x4 acc[4] = {};
#pragma unroll
  for (int kk = 0; kk < KSTEPS; ++kk) {
    f16x8 af = Ap[kk * 4];
#pragma unroll
    for (int c = 0; c < 4; ++c) {
      int col = c * 16 + r16;
      f16x8 bf = Bs[(col * UPC + kk * 4 + ko) ^ (col & 7)];
      acc[c] = __builtin_amdgcn_mfma_f32_16x16x32_f16(af, bf, acc[c], 0, 0, 0);
    }
  }
  int h = colBase >> 6;
  float alv[4], arv[4];
#pragma unroll
  for (int c = 0; c < 4; ++c) {
    alv[c] = al[colBase + c * 16 + r16];
    arv[c] = ar[colBase + c * 16 + r16];
  }
#pragma unroll
  for (int r = 0; r < 4; ++r) {
    int row = rb + (lane >> 4) * 4 + r;
    bool ok = row < M;
    float pl = 0.f, pr = 0.f;
#pragma unroll
    for (int c = 0; c < 4; ++c) {
      float v = acc[c][r];
      if (ok) Ch[(size_t)row * Ncols + colBase + c * 16 + r16] = __float2half(v);
      pl += v * alv[c];
      pr += v * arv[c];
    }
#pragma unroll
    for (int o = 8; o > 0; o >>= 1) {
      pl += __shfl_xor(pl, o);
      pr += __shfl_xor(pr, o);
    }
    if (r16 == 0 && ok) {
      el[(size_t)row * H + h] = pl;
      er[(size_t)row * H + h] = pr;
    }
  }
}

// ---- merged dispatch: CSR scatter blocks FIRST, then GEMM1 tiles ----
#define GEMM1_RB ((N_NODES + 63) / 64)
#define GEMM1_BLOCKS (8 * GEMM1_RB)
#define SCAT_BLOCKS ((N_EDGES + 255) / 256)
__global__ __launch_bounds__(256) void gemm1_scatter_kernel(
    const __half* __restrict__ A, const __half* __restrict__ BT,
    __half* __restrict__ Ch, const float* __restrict__ al,
    const float* __restrict__ ar, float* __restrict__ el,
    float* __restrict__ er,
    const int* __restrict__ src, const int* __restrict__ dst,
    int* __restrict__ cursor8, int* __restrict__ src_csr) {
  __shared__ f16x8 Bs[256 * 8];  // 32 KB (KSTEPS=8)
  if (blockIdx.x < SCAT_BLOCKS) {
    int e = blockIdx.x * 256 + threadIdx.x;
    if (e < N_EDGES) {
      int p = atomicAdd(&cursor8[dst[e] * 8 + (e & 7)], 1);
      src_csr[p] = src[e];
    }
    return;
  }
  int bid = blockIdx.x - SCAT_BLOCKS;
  gemm_tile<IN_SIZE / 32>((bid >> 3) * 64, (bid & 7) * 64,
                          A, BT, Ch, al, ar, el, er, N_NODES, F1, H1, Bs);
}

// ---- layer-2 GEMM: one wave per block, 16 rows x 64 cols, no LDS ----
__global__ __launch_bounds__(64) void gemm2_kernel(
    const __half* __restrict__ A, const __half* __restrict__ BT,
    __half* __restrict__ Ch, const float* __restrict__ al,
    const float* __restrict__ ar, float* __restrict__ el,
    float* __restrict__ er) {
  constexpr int K = F1;
  constexpr int KSTEPS = F1 / 32;
  int lane = threadIdx.x & 63;
  int rowBase = blockIdx.x * 16;
  int r16 = lane & 15, ko = lane >> 4;
  int arow = rowBase + r16;
  if (arow >= N_NODES) arow = N_NODES - 1;
  const f16x8* Ap = reinterpret_cast<const f16x8*>(A + (size_t)arow * K + ko * 8);
  const __half* Bbase = BT + ko * 8;
  f32x4 acc[4] = {};
#pragma unroll
  for (int kk = 0; kk < KSTEPS; ++kk) {
    f16x8 af = Ap[kk * 4];
#pragma unroll
    for (int c = 0; c < 4; ++c) {
      f16x8 bf = *reinterpret_cast<const f16x8*>(
          Bbase + (size_t)(c * 16 + r16) * K + kk * 32);
      acc[c] = __builtin_amdgcn_mfma_f32_16x16x32_f16(af, bf, acc[c], 0, 0, 0);
    }
  }
  float alv[4], arv[4];
#pragma unroll
  for (int c = 0; c < 4; ++c) {
    alv[c] = al[c * 16 + r16];
    arv[c] = ar[c * 16 + r16];
  }
#pragma unroll
  for (int r = 0; r < 4; ++r) {
    int row = rowBase + ko * 4 + r;
    bool ok = row < N_NODES;
    float pl = 0.f, pr = 0.f;
#pragma unroll
    for (int c = 0; c < 4; ++c) {
      float v = acc[c][r];
      if (ok) Ch[(size_t)row * F2 + c * 16 + r16] = __float2half(v);
      pl += v * alv[c];
      pr += v * arv[c];
    }
#pragma unroll
    for (int o = 8; o > 0; o >>= 1) {
      pl += __shfl_xor(pl, o);
      pr += __shfl_xor(pr, o);
    }
    if (r16 == 0 && ok) {
      el[row] = pl;
      er[row] = pr;
    }
  }
}

__device__ __forceinline__ float leaky_exp(float v) {
  v = (v >= 0.f) ? v : 0.2f * v;
  return __expf(fminf(v, 80.f));
}

// ---- aggregation layer 1 (exp fused): block = node, wave = 128-ch tile ----
__global__ __launch_bounds__(256) void agg1_kernel(
    const int* __restrict__ row_off, const int* __restrict__ src_csr,
    const float* __restrict__ el, const float* __restrict__ er,
    const __half* __restrict__ fth, const float* __restrict__ bias,
    __half* __restrict__ out, const int* __restrict__ nord) {
  int t = threadIdx.x;
  int w = t >> 6, lane = t & 63;
  int n = nord[blockIdx.x];
  int e = lane >> 4;
  int sub = lane & 15;
  int chb = w * 128 + sub * 8;
  int h = chb >> 6;
  int beg = row_off[n], end = row_off[n + 1];
  float er_h = er[n * 8 + h];
  float s_run = 0.f;
  float acc[8] = {0.f, 0.f, 0.f, 0.f, 0.f, 0.f, 0.f, 0.f};
  if (beg < end) {
    int iA = min(beg + e, end - 1);
    bool okA = (beg + e) < end;
    int sA = src_csr[iA];
    int iB = min(beg + 4 + e, end - 1);
    bool okB = (beg + 4 + e) < end;
    int sB = src_csr[iB];
    float elA = el[sA * 8 + h];
    uint4 ftA = *reinterpret_cast<const uint4*>(fth + (size_t)sA * F1 + chb);
    for (int c = beg; c < end; c += 4) {
      int iC = min(c + 8 + e, end - 1);
      bool okC = (c + 8 + e) < end;
      int sC = src_csr[iC];
      float elB = el[sB * 8 + h];
      uint4 ftB = *reinterpret_cast<const uint4*>(fth + (size_t)sB * F1 + chb);
      float ex = okA ? leaky_exp(elA + er_h) : 0.f;
      float2 f0 = __half22float2(*reinterpret_cast<const __half2*>(&ftA.x));
      float2 f1 = __half22float2(*reinterpret_cast<const __half2*>(&ftA.y));
      float2 f2 = __half22float2(*reinterpret_cast<const __half2*>(&ftA.z));
      float2 f3 = __half22float2(*reinterpret_cast<const __half2*>(&ftA.w));
      acc[0] += ex * f0.x; acc[1] += ex * f0.y;
      acc[2] += ex * f1.x; acc[3] += ex * f1.y;
      acc[4] += ex * f2.x; acc[5] += ex * f2.y;
      acc[6] += ex * f3.x; acc[7] += ex * f3.y;
      s_run += ex;
      sA = sB; okA = okB; elA = elB; ftA = ftB;
      sB = sC; okB = okC;
    }
  }
#pragma unroll
  for (int i = 0; i < 8; ++i) {
    acc[i] += __shfl_xor(acc[i], 16);
    acc[i] += __shfl_xor(acc[i], 32);
  }
  s_run += __shfl_xor(s_run, 16);
  s_run += __shfl_xor(s_run, 32);
  if (e == 0) {
    float inv = (s_run > 0.f) ? (1.f / s_run) : 0.f;
    uint4 pack;
    __half2* ph = reinterpret_cast<__half2*>(&pack);
#pragma unroll
    for (int i = 0; i < 4; ++i) {
      float v0 = acc[2 * i + 0] * inv + bias[chb + 2 * i + 0];
      float v1 = acc[2 * i + 1] * inv + bias[chb + 2 * i + 1];
      v0 = (v0 > 0.f) ? v0 : (__expf(v0) - 1.f);  // ELU
      v1 = (v1 > 0.f) ? v1 : (__expf(v1) - 1.f);
      ph[i] = __floats2half2_rn(v0, v1);
    }
    *reinterpret_cast<uint4*>(out + (size_t)n * F1 + chb) = pack;
  }
}

// ---- aggregation layer 2 (H=1, exp fused): wave per node ----
template <int NPB>
__global__ __launch_bounds__(NPB * 64) void agg2_kernel(
    const int* __restrict__ row_off, const int* __restrict__ src_csr,
    const float* __restrict__ el, const float* __restrict__ er,
    const __half* __restrict__ fth, const float* __restrict__ bias,
    float* __restrict__ out, const int* __restrict__ nord) {
  int t = threadIdx.x;
  int w = t >> 6, lane = t & 63;
  int n = nord[blockIdx.x * NPB + w];
  int e = lane >> 3;
  int q = lane & 7;
  int chb = q * 8;
  int beg = row_off[n], end = row_off[n + 1];
  float er_n = er[n];
  float s_run = 0.f;
  float acc[8] = {0.f, 0.f, 0.f, 0.f, 0.f, 0.f, 0.f, 0.f};
  if (beg < end) {
    int iA = min(beg + e, end - 1);
    bool okA = (beg + e) < end;
    int sA = src_csr[iA];
    int iB = min(beg + 8 + e, end - 1);
    bool okB = (beg + 8 + e) < end;
    int sB = src_csr[iB];
    float elA = el[sA];
    uint4 ftA = *reinterpret_cast<const uint4*>(fth + (size_t)sA * F2 + chb);
    for (int c = beg; c < end; c += 8) {
      int iC = min(c + 16 + e, end - 1);
      bool okC = (c + 16 + e) < end;
      int sC = src_csr[iC];
      float elB = el[sB];
      uint4 ftB = *reinterpret_cast<const uint4*>(fth + (size_t)sB * F2 + chb);
      float ex = okA ? leaky_exp(elA + er_n) : 0.f;
      float2 f0 = __half22float2(*reinterpret_cast<const __half2*>(&ftA.x));
      float2 f1 = __half22float2(*reinterpret_cast<const __half2*>(&ftA.y));
      float2 f2 = __half22float2(*reinterpret_cast<const __half2*>(&ftA.z));
      float2 f3 = __half22float2(*reinterpret_cast<const __half2*>(&ftA.w));
      acc[0] += ex * f0.x; acc[1] += ex * f0.y;
      acc[2] += ex * f1.x; acc[3] += ex * f1.y;
      acc[4] += ex * f2.x; acc[5] += ex * f2.y;
      acc[6] += ex * f3.x; acc[7] += ex * f3.y;
      s_run += ex;
      sA = sB; okA = okB; elA = elB; ftA = ftB;
      sB = sC; okB = okC;
    }
  }
#pragma unroll
  for (int i = 0; i < 8; ++i) {
    acc[i] += __shfl_xor(acc[i], 8);
    acc[i] += __shfl_xor(acc[i], 16);
    acc[i] += __shfl_xor(acc[i], 32);
  }
  s_run += __shfl_xor(s_run, 8);
  s_run += __shfl_xor(s_run, 16);
  s_run += __shfl_xor(s_run, 32);
  if (e == 0) {
    float inv = (s_run > 0.f) ? (1.f / s_run) : 0.f;
    float o[8];
#pragma unroll
    for (int i = 0; i < 8; ++i) o[i] = acc[i] * inv + bias[chb + i];
    float* op = &out[(size_t)n * F2 + chb];
    *reinterpret_cast<float4*>(op) = make_float4(o[0], o[1], o[2], o[3]);
    *reinterpret_cast<float4*>(op + 4) = make_float4(o[4], o[5], o[6], o[7]);
  }
}

extern "C" void kernel_launch(void* const* d_in, const int* in_sizes, int n_in,
                              void* d_out, int out_size, void* d_ws, size_t ws_size,
                              hipStream_t stream) {
  const float* x   = (const float*)d_in[0];
  const int*   src = (const int*)d_in[1];
  const int*   dst = (const int*)d_in[2];
  const float* W1  = (const float*)d_in[3];
  const float* al1 = (const float*)d_in[4];
  const float* ar1 = (const float*)d_in[5];
  const float* b1  = (const float*)d_in[6];
  const float* W2  = (const float*)d_in[7];
  const float* al2 = (const float*)d_in[8];
  const float* ar2 = (const float*)d_in[9];
  const float* b2  = (const float*)d_in[10];
  float* out = (float*)d_out;

  char* ws = (char*)d_ws;
  size_t off = 0;
  auto alloc = [&](size_t bytes) -> void* {
    void* p = ws + off;
    off += (bytes + 255) & ~(size_t)255;
    return p;
  };
  size_t zbeg = off;
  int* counts8 = (int*)alloc((size_t)N_NODES * 8 * 4);
  int* dbins   = (int*)alloc(129 * 4);
  size_t zend = off;
  int* deg     = (int*)alloc((size_t)N_NODES * 4);
  int* bsum    = (int*)alloc(NSCAN_BLOCKS * 4);
  int* bbase   = (int*)alloc(NSCAN_BLOCKS * 4);
  int* dcur    = (int*)alloc(129 * 4);
  int* cursor8 = (int*)alloc((size_t)N_NODES * 8 * 4);
  int* nord    = (int*)alloc((size_t)N_NODES * 4);
  __half* xh   = (__half*)alloc((size_t)N_NODES * IN_SIZE * 2);
  __half* W1T  = (__half*)alloc((size_t)IN_SIZE * F1 * 2);
  __half* W2T  = (__half*)alloc((size_t)F1 * F2 * 2);
  __half* ft1h = (__half*)alloc((size_t)N_NODES * F1 * 2);
  __half* h1h  = (__half*)alloc((size_t)N_NODES * F1 * 2);
  __half* ft2h = (__half*)alloc((size_t)N_NODES * F2 * 2);
  float* el1 = (float*)alloc((size_t)N_NODES * H1 * 4);
  float* er1 = (float*)alloc((size_t)N_NODES * H1 * 4);
  float* el2 = (float*)alloc((size_t)N_NODES * 4);
  float* er2 = (float*)alloc((size_t)N_NODES * 4);
  int* row_off = (int*)alloc((size_t)(N_NODES + 1) * 4);
  int* src_csr = (int*)alloc((size_t)N_EDGES * 4);
  (void)ws_size; (void)in_sizes; (void)n_in; (void)out_size;

  hipMemsetAsync(ws + zbeg, 0, zend - zbeg, stream);

  dim3 b256(256);
  int prep_total = PREP_X + PREP_W1 + PREP_W2 + N_EDGES;

  // prep (x cvt + W transposes + dst histogram)
  prep_kernel<<<(prep_total + 255) / 256, b256, 0, stream>>>(
      x, xh, W1, W1T, W2, W2T, dst, counts8);
  // parallel CSR-prep scan (3 cheap dispatches replacing the 50 us serial one)
  deg_kernel<<<NSCAN_BLOCKS, b256, 0, stream>>>(counts8, deg, dbins, bsum);
  scan_small_kernel<<<1, b256, 0, stream>>>(bsum, dbins, bbase, dcur, row_off);
  finalize_kernel<<<NSCAN_BLOCKS, b256, 0, stream>>>(
      counts8, deg, bbase, row_off, cursor8, dcur, nord);

  // ---- layer 1: scatter + GEMM1 merged (scatter blocks first) ----
  gemm1_scatter_kernel<<<SCAT_BLOCKS + GEMM1_BLOCKS, b256, 0, stream>>>(
      xh, W1T, ft1h, al1, ar1, el1, er1, src, dst, cursor8, src_csr);
  agg1_kernel<<<N_NODES, b256, 0, stream>>>(
      row_off, src_csr, el1, er1, ft1h, b1, h1h, nord);

  // ---- layer 2 ----
  gemm2_kernel<<<(N_NODES + 15) / 16, 64, 0, stream>>>(
      h1h, W2T, ft2h, al2, ar2, el2, er2);
  agg2_kernel<4><<<N_NODES / 4, b256, 0, stream>>>(
      row_off, src_csr, el2, er2, ft2h, b2, out, nord);
}

// Round 16
// 155.820 us; speedup vs baseline: 1.0244x; 1.0047x over previous
//
#include <hip/hip_runtime.h>
#include <hip/hip_bf16.h>
#include <hip/hip_fp16.h>
#include <math.h>

#define N_NODES 10000
#define N_EDGES 320000
#define IN_SIZE 256
#define H1 8
#define D1 64
#define F1 512
#define H2 1
#define D2 64
#define F2 64

using f16x8 = __attribute__((ext_vector_type(8))) _Float16;
using f32x4 = __attribute__((ext_vector_type(4))) float;

// ---- fused prep: x->f16, W1^T->f16, W2^T->f16, dst histogram (4 sub-counters) ----
#define PREP_X (N_NODES * IN_SIZE / 4)
#define PREP_W1 (IN_SIZE * F1)
#define PREP_W2 (F1 * F2)
__global__ void prep_kernel(const float* __restrict__ x, __half* __restrict__ xh,
                            const float* __restrict__ W1, __half* __restrict__ W1T,
                            const float* __restrict__ W2, __half* __restrict__ W2T,
                            const int* __restrict__ dst, int* __restrict__ counts4) {
  int i = blockIdx.x * blockDim.x + threadIdx.x;
  if (i < PREP_X) {
    float4 v = reinterpret_cast<const float4*>(x)[i];
    reinterpret_cast<__half2*>(xh)[i * 2 + 0] = __floats2half2_rn(v.x, v.y);
    reinterpret_cast<__half2*>(xh)[i * 2 + 1] = __floats2half2_rn(v.z, v.w);
    return;
  }
  i -= PREP_X;
  if (i < PREP_W1) {
    int k = i / F1, n = i % F1;
    W1T[(size_t)n * IN_SIZE + k] = __float2half(W1[i]);
    return;
  }
  i -= PREP_W1;
  if (i < PREP_W2) {
    int k = i / F2, n = i % F2;
    W2T[(size_t)n * F1 + k] = __float2half(W2[i]);
    return;
  }
  i -= PREP_W2;
  if (i < N_EDGES) atomicAdd(&counts4[dst[i] * 4 + (i & 3)], 1);
}

// ---- parallel CSR-prep scan, stage 1: per-node degree + bins + block sums ----
#define NSCAN_BLOCKS ((N_NODES + 255) / 256)
__global__ __launch_bounds__(256) void deg_kernel(const int* __restrict__ counts4,
                                                  int* __restrict__ deg,
                                                  int* __restrict__ dbins,
                                                  int* __restrict__ bsum) {
  __shared__ int red[256];
  int tid = threadIdx.x;
  int i = blockIdx.x * 256 + tid;
  int d = 0;
  if (i < N_NODES) {
#pragma unroll
    for (int j = 0; j < 4; ++j) d += counts4[i * 4 + j];
    deg[i] = d;
    atomicAdd(&dbins[min(d, 128)], 1);
  }
  red[tid] = d;
  __syncthreads();
  for (int o = 128; o > 0; o >>= 1) {
    if (tid < o) red[tid] += red[tid + o];
    __syncthreads();
  }
  if (tid == 0) bsum[blockIdx.x] = red[0];
}

// ---- stage 2: tiny serial scans (LDS-staged), 1 block ----
__global__ __launch_bounds__(256) void scan_small_kernel(const int* __restrict__ bsum,
                                                         const int* __restrict__ dbins,
                                                         int* __restrict__ bbase,
                                                         int* __restrict__ dcur,
                                                         int* __restrict__ row_off) {
  __shared__ int lb[NSCAN_BLOCKS];
  __shared__ int ld[129];
  int tid = threadIdx.x;
  if (tid < NSCAN_BLOCKS) lb[tid] = bsum[tid];
  if (tid < 129) ld[tid] = dbins[tid];
  __syncthreads();
  if (tid == 0) {
    int run = 0;
    for (int b = 0; b < NSCAN_BLOCKS; ++b) { int c = lb[b]; lb[b] = run; run += c; }
    row_off[N_NODES] = run;
    int r = 0;
    for (int d = 128; d >= 0; --d) { int c = ld[d]; ld[d] = r; r += c; }
  }
  __syncthreads();
  if (tid < NSCAN_BLOCKS) bbase[tid] = lb[tid];
  if (tid < 129) dcur[tid] = ld[tid];
}

// ---- stage 3: per-block prefix scan -> row_off, cursor4, nord ----
__global__ __launch_bounds__(256) void finalize_kernel(const int* __restrict__ counts4,
                                                       const int* __restrict__ deg,
                                                       const int* __restrict__ bbase,
                                                       int* __restrict__ row_off,
                                                       int* __restrict__ cursor4,
                                                       int* __restrict__ dcur,
                                                       int* __restrict__ nord) {
  __shared__ int pre[256];
  int tid = threadIdx.x;
  int i = blockIdx.x * 256 + tid;
  int d = (i < N_NODES) ? deg[i] : 0;
  pre[tid] = d;
  __syncthreads();
  for (int o = 1; o < 256; o <<= 1) {
    int v = (tid >= o) ? pre[tid - o] : 0;
    __syncthreads();
    pre[tid] += v;
    __syncthreads();
  }
  if (i < N_NODES) {
    int base = bbase[blockIdx.x] + pre[tid] - d;  // exclusive prefix
    row_off[i] = base;
    int acc = base;
#pragma unroll
    for (int j = 0; j < 4; ++j) {
      cursor4[i * 4 + j] = acc;
      acc += counts4[i * 4 + j];
    }
    int pos = atomicAdd(&dcur[min(d, 128)], 1);
    nord[pos] = i;
  }
}

// ---- shared LDS-staged MFMA GEMM tile (64 rows x 64 cols per block) ----
template <int KSTEPS>
__device__ __forceinline__ void gemm_tile(
    int rowBase, int colBase, const __half* __restrict__ A,
    const __half* __restrict__ BT, __half* __restrict__ Ch,
    const float* __restrict__ al, const float* __restrict__ ar,
    float* __restrict__ el, float* __restrict__ er,
    int M, int Ncols, int H, f16x8* Bs) {
  constexpr int K = KSTEPS * 32;
  constexpr int UPC = 4 * KSTEPS;  // 16B units per column
  int tid = threadIdx.x;
  for (int u = tid; u < 64 * UPC; u += 256) {
    int col = u / UPC;
    int off = u % UPC;
    f16x8 v = *reinterpret_cast<const f16x8*>(BT + (size_t)(colBase + col) * K + off * 8);
    Bs[u ^ (col & 7)] = v;
  }
  __syncthreads();
  int w = tid >> 6, lane = tid & 63;
  int r16 = lane & 15, ko = lane >> 4;
  int rb = rowBase + w * 16;
  int arow = rb + r16;
  if (arow >= M) arow = M - 1;
  const f16x8* Ap = reinterpret_cast<const f16x8*>(A + (size_t)arow * K + ko * 8);
  f32x4 acc[4] = {};
#pragma unroll
  for (int kk = 0; kk < KSTEPS; ++kk) {
    f16x8 af = Ap[kk * 4];
#pragma unroll
    for (int c = 0; c < 4; ++c) {
      int col = c * 16 + r16;
      f16x8 bf = Bs[(col * UPC + kk * 4 + ko) ^ (col & 7)];
      acc[c] = __builtin_amdgcn_mfma_f32_16x16x32_f16(af, bf, acc[c], 0, 0, 0);
    }
  }
  int h = colBase >> 6;
  float alv[4], arv[4];
#pragma unroll
  for (int c = 0; c < 4; ++c) {
    alv[c] = al[colBase + c * 16 + r16];
    arv[c] = ar[colBase + c * 16 + r16];
  }
#pragma unroll
  for (int r = 0; r < 4; ++r) {
    int row = rb + (lane >> 4) * 4 + r;
    bool ok = row < M;
    float pl = 0.f, pr = 0.f;
#pragma unroll
    for (int c = 0; c < 4; ++c) {
      float v = acc[c][r];
      if (ok) Ch[(size_t)row * Ncols + colBase + c * 16 + r16] = __float2half(v);
      pl += v * alv[c];
      pr += v * arv[c];
    }
#pragma unroll
    for (int o = 8; o > 0; o >>= 1) {
      pl += __shfl_xor(pl, o);
      pr += __shfl_xor(pr, o);
    }
    if (r16 == 0 && ok) {
      el[(size_t)row * H + h] = pl;
      er[(size_t)row * H + h] = pr;
    }
  }
}

// ---- merged dispatch: GEMM1 tiles first, then CSR scatter (r13 ordering) ----
#define GEMM1_RB ((N_NODES + 63) / 64)
#define GEMM1_BLOCKS (8 * GEMM1_RB)
#define SCAT_BLOCKS ((N_EDGES + 255) / 256)
__global__ __launch_bounds__(256) void gemm1_scatter_kernel(
    const __half* __restrict__ A, const __half* __restrict__ BT,
    __half* __restrict__ Ch, const float* __restrict__ al,
    const float* __restrict__ ar, float* __restrict__ el,
    float* __restrict__ er,
    const int* __restrict__ src, const int* __restrict__ dst,
    int* __restrict__ cursor4, int* __restrict__ src_csr) {
  __shared__ f16x8 Bs[256 * 8];  // 32 KB (KSTEPS=8)
  if (blockIdx.x >= GEMM1_BLOCKS) {
    int e = (blockIdx.x - GEMM1_BLOCKS) * 256 + threadIdx.x;
    if (e < N_EDGES) {
      int p = atomicAdd(&cursor4[dst[e] * 4 + (e & 3)], 1);
      src_csr[p] = src[e];
    }
    return;
  }
  gemm_tile<IN_SIZE / 32>((blockIdx.x >> 3) * 64, (blockIdx.x & 7) * 64,
                          A, BT, Ch, al, ar, el, er, N_NODES, F1, H1, Bs);
}

// ---- standalone LDS GEMM (layer 2, r13 version) ----
template <int KSTEPS>
__global__ __launch_bounds__(256) void gemm_lds(
    const __half* __restrict__ A, const __half* __restrict__ BT,
    __half* __restrict__ Ch, const float* __restrict__ al,
    const float* __restrict__ ar, float* __restrict__ el,
    float* __restrict__ er, int M, int Ncols, int H) {
  __shared__ f16x8 Bs[64 * 4 * KSTEPS];
  gemm_tile<KSTEPS>(blockIdx.y * 64, blockIdx.x * 64,
                    A, BT, Ch, al, ar, el, er, M, Ncols, H, Bs);
}

__device__ __forceinline__ float leaky_exp(float v) {
  v = (v >= 0.f) ? v : 0.2f * v;
  return __expf(fminf(v, 80.f));
}

// ---- aggregation layer 1 (exp fused): block = node, wave = 128-ch tile ----
__global__ __launch_bounds__(256) void agg1_kernel(
    const int* __restrict__ row_off, const int* __restrict__ src_csr,
    const float* __restrict__ el, const float* __restrict__ er,
    const __half* __restrict__ fth, const float* __restrict__ bias,
    __half* __restrict__ out, const int* __restrict__ nord) {
  int t = threadIdx.x;
  int w = t >> 6, lane = t & 63;
  int n = nord[blockIdx.x];
  int e = lane >> 4;
  int sub = lane & 15;
  int chb = w * 128 + sub * 8;
  int h = chb >> 6;
  int beg = row_off[n], end = row_off[n + 1];
  float er_h = er[n * 8 + h];
  float s_run = 0.f;
  float acc[8] = {0.f, 0.f, 0.f, 0.f, 0.f, 0.f, 0.f, 0.f};
  if (beg < end) {
    int iA = min(beg + e, end - 1);
    bool okA = (beg + e) < end;
    int sA = src_csr[iA];
    int iB = min(beg + 4 + e, end - 1);
    bool okB = (beg + 4 + e) < end;
    int sB = src_csr[iB];
    float elA = el[sA * 8 + h];
    uint4 ftA = *reinterpret_cast<const uint4*>(fth + (size_t)sA * F1 + chb);
    for (int c = beg; c < end; c += 4) {
      int iC = min(c + 8 + e, end - 1);
      bool okC = (c + 8 + e) < end;
      int sC = src_csr[iC];
      float elB = el[sB * 8 + h];
      uint4 ftB = *reinterpret_cast<const uint4*>(fth + (size_t)sB * F1 + chb);
      float ex = okA ? leaky_exp(elA + er_h) : 0.f;
      float2 f0 = __half22float2(*reinterpret_cast<const __half2*>(&ftA.x));
      float2 f1 = __half22float2(*reinterpret_cast<const __half2*>(&ftA.y));
      float2 f2 = __half22float2(*reinterpret_cast<const __half2*>(&ftA.z));
      float2 f3 = __half22float2(*reinterpret_cast<const __half2*>(&ftA.w));
      acc[0] += ex * f0.x; acc[1] += ex * f0.y;
      acc[2] += ex * f1.x; acc[3] += ex * f1.y;
      acc[4] += ex * f2.x; acc[5] += ex * f2.y;
      acc[6] += ex * f3.x; acc[7] += ex * f3.y;
      s_run += ex;
      sA = sB; okA = okB; elA = elB; ftA = ftB;
      sB = sC; okB = okC;
    }
  }
#pragma unroll
  for (int i = 0; i < 8; ++i) {
    acc[i] += __shfl_xor(acc[i], 16);
    acc[i] += __shfl_xor(acc[i], 32);
  }
  s_run += __shfl_xor(s_run, 16);
  s_run += __shfl_xor(s_run, 32);
  if (e == 0) {
    float inv = (s_run > 0.f) ? (1.f / s_run) : 0.f;
    uint4 pack;
    __half2* ph = reinterpret_cast<__half2*>(&pack);
#pragma unroll
    for (int i = 0; i < 4; ++i) {
      float v0 = acc[2 * i + 0] * inv + bias[chb + 2 * i + 0];
      float v1 = acc[2 * i + 1] * inv + bias[chb + 2 * i + 1];
      v0 = (v0 > 0.f) ? v0 : (__expf(v0) - 1.f);  // ELU
      v1 = (v1 > 0.f) ? v1 : (__expf(v1) - 1.f);
      ph[i] = __floats2half2_rn(v0, v1);
    }
    *reinterpret_cast<uint4*>(out + (size_t)n * F1 + chb) = pack;
  }
}

// ---- aggregation layer 2 (H=1, exp fused): wave per node ----
template <int NPB>
__global__ __launch_bounds__(NPB * 64) void agg2_kernel(
    const int* __restrict__ row_off, const int* __restrict__ src_csr,
    const float* __restrict__ el, const float* __restrict__ er,
    const __half* __restrict__ fth, const float* __restrict__ bias,
    float* __restrict__ out, const int* __restrict__ nord) {
  int t = threadIdx.x;
  int w = t >> 6, lane = t & 63;
  int n = nord[blockIdx.x * NPB + w];
  int e = lane >> 3;
  int q = lane & 7;
  int chb = q * 8;
  int beg = row_off[n], end = row_off[n + 1];
  float er_n = er[n];
  float s_run = 0.f;
  float acc[8] = {0.f, 0.f, 0.f, 0.f, 0.f, 0.f, 0.f, 0.f};
  if (beg < end) {
    int iA = min(beg + e, end - 1);
    bool okA = (beg + e) < end;
    int sA = src_csr[iA];
    int iB = min(beg + 8 + e, end - 1);
    bool okB = (beg + 8 + e) < end;
    int sB = src_csr[iB];
    float elA = el[sA];
    uint4 ftA = *reinterpret_cast<const uint4*>(fth + (size_t)sA * F2 + chb);
    for (int c = beg; c < end; c += 8) {
      int iC = min(c + 16 + e, end - 1);
      bool okC = (c + 16 + e) < end;
      int sC = src_csr[iC];
      float elB = el[sB];
      uint4 ftB = *reinterpret_cast<const uint4*>(fth + (size_t)sB * F2 + chb);
      float ex = okA ? leaky_exp(elA + er_n) : 0.f;
      float2 f0 = __half22float2(*reinterpret_cast<const __half2*>(&ftA.x));
      float2 f1 = __half22float2(*reinterpret_cast<const __half2*>(&ftA.y));
      float2 f2 = __half22float2(*reinterpret_cast<const __half2*>(&ftA.z));
      float2 f3 = __half22float2(*reinterpret_cast<const __half2*>(&ftA.w));
      acc[0] += ex * f0.x; acc[1] += ex * f0.y;
      acc[2] += ex * f1.x; acc[3] += ex * f1.y;
      acc[4] += ex * f2.x; acc[5] += ex * f2.y;
      acc[6] += ex * f3.x; acc[7] += ex * f3.y;
      s_run += ex;
      sA = sB; okA = okB; elA = elB; ftA = ftB;
      sB = sC; okB = okC;
    }
  }
#pragma unroll
  for (int i = 0; i < 8; ++i) {
    acc[i] += __shfl_xor(acc[i], 8);
    acc[i] += __shfl_xor(acc[i], 16);
    acc[i] += __shfl_xor(acc[i], 32);
  }
  s_run += __shfl_xor(s_run, 8);
  s_run += __shfl_xor(s_run, 16);
  s_run += __shfl_xor(s_run, 32);
  if (e == 0) {
    float inv = (s_run > 0.f) ? (1.f / s_run) : 0.f;
    float o[8];
#pragma unroll
    for (int i = 0; i < 8; ++i) o[i] = acc[i] * inv + bias[chb + i];
    float* op = &out[(size_t)n * F2 + chb];
    *reinterpret_cast<float4*>(op) = make_float4(o[0], o[1], o[2], o[3]);
    *reinterpret_cast<float4*>(op + 4) = make_float4(o[4], o[5], o[6], o[7]);
  }
}

extern "C" void kernel_launch(void* const* d_in, const int* in_sizes, int n_in,
                              void* d_out, int out_size, void* d_ws, size_t ws_size,
                              hipStream_t stream) {
  const float* x   = (const float*)d_in[0];
  const int*   src = (const int*)d_in[1];
  const int*   dst = (const int*)d_in[2];
  const float* W1  = (const float*)d_in[3];
  const float* al1 = (const float*)d_in[4];
  const float* ar1 = (const float*)d_in[5];
  const float* b1  = (const float*)d_in[6];
  const float* W2  = (const float*)d_in[7];
  const float* al2 = (const float*)d_in[8];
  const float* ar2 = (const float*)d_in[9];
  const float* b2  = (const float*)d_in[10];
  float* out = (float*)d_out;

  char* ws = (char*)d_ws;
  size_t off = 0;
  auto alloc = [&](size_t bytes) -> void* {
    void* p = ws + off;
    off += (bytes + 255) & ~(size_t)255;
    return p;
  };
  size_t zbeg = off;
  int* counts4 = (int*)alloc((size_t)N_NODES * 4 * 4);
  int* dbins   = (int*)alloc(129 * 4);
  size_t zend = off;
  int* deg     = (int*)alloc((size_t)N_NODES * 4);
  int* bsum    = (int*)alloc(NSCAN_BLOCKS * 4);
  int* bbase   = (int*)alloc(NSCAN_BLOCKS * 4);
  int* dcur    = (int*)alloc(129 * 4);
  int* cursor4 = (int*)alloc((size_t)N_NODES * 4 * 4);
  int* nord    = (int*)alloc((size_t)N_NODES * 4);
  __half* xh   = (__half*)alloc((size_t)N_NODES * IN_SIZE * 2);
  __half* W1T  = (__half*)alloc((size_t)IN_SIZE * F1 * 2);
  __half* W2T  = (__half*)alloc((size_t)F1 * F2 * 2);
  __half* ft1h = (__half*)alloc((size_t)N_NODES * F1 * 2);
  __half* h1h  = (__half*)alloc((size_t)N_NODES * F1 * 2);
  __half* ft2h = (__half*)alloc((size_t)N_NODES * F2 * 2);
  float* el1 = (float*)alloc((size_t)N_NODES * H1 * 4);
  float* er1 = (float*)alloc((size_t)N_NODES * H1 * 4);
  float* el2 = (float*)alloc((size_t)N_NODES * 4);
  float* er2 = (float*)alloc((size_t)N_NODES * 4);
  int* row_off = (int*)alloc((size_t)(N_NODES + 1) * 4);
  int* src_csr = (int*)alloc((size_t)N_EDGES * 4);
  (void)ws_size; (void)in_sizes; (void)n_in; (void)out_size;

  hipMemsetAsync(ws + zbeg, 0, zend - zbeg, stream);

  dim3 b256(256);
  int prep_total = PREP_X + PREP_W1 + PREP_W2 + N_EDGES;

  // prep (x cvt + W transposes + dst histogram)
  prep_kernel<<<(prep_total + 255) / 256, b256, 0, stream>>>(
      x, xh, W1, W1T, W2, W2T, dst, counts4);
  // parallel CSR-prep scan
  deg_kernel<<<NSCAN_BLOCKS, b256, 0, stream>>>(counts4, deg, dbins, bsum);
  scan_small_kernel<<<1, b256, 0, stream>>>(bsum, dbins, bbase, dcur, row_off);
  finalize_kernel<<<NSCAN_BLOCKS, b256, 0, stream>>>(
      counts4, deg, bbase, row_off, cursor4, dcur, nord);

  // ---- layer 1: GEMM1 tiles + scatter merged (gemm blocks first, r13) ----
  gemm1_scatter_kernel<<<GEMM1_BLOCKS + SCAT_BLOCKS, b256, 0, stream>>>(
      xh, W1T, ft1h, al1, ar1, el1, er1, src, dst, cursor4, src_csr);
  agg1_kernel<<<N_NODES, b256, 0, stream>>>(
      row_off, src_csr, el1, er1, ft1h, b1, h1h, nord);

  // ---- layer 2 ----
  gemm_lds<F1 / 32><<<dim3(F2 / 64, (N_NODES + 63) / 64), b256, 0, stream>>>(
      h1h, W2T, ft2h, al2, ar2, el2, er2, N_NODES, F2, H2);
  agg2_kernel<4><<<N_NODES / 4, b256, 0, stream>>>(
      row_off, src_csr, el2, er2, ft2h, b2, out, nord);
}

// Round 17
// 109.324 us; speedup vs baseline: 1.4602x; 1.4253x over previous
//
#include <hip/hip_runtime.h>
#include <hip/hip_bf16.h>
#include <hip/hip_fp16.h>
#include <math.h>

#define N_NODES 10000
#define N_EDGES 320000
#define IN_SIZE 256
#define H1 8
#define D1 64
#define F1 512
#define H2 1
#define D2 64
#define F2 64
#define SLOT_STRIDE 128   // padded per-node edge bucket; P(deg>128) ~ e^-32

using f16x8 = __attribute__((ext_vector_type(8))) _Float16;
using f32x4 = __attribute__((ext_vector_type(4))) float;

// ---- fused prep: x->f16, W1^T->f16, W2^T->f16, AND direct CSR-bucket scatter ----
#define PREP_X (N_NODES * IN_SIZE / 4)
#define PREP_W1 (IN_SIZE * F1)
#define PREP_W2 (F1 * F2)
__global__ void prep_kernel(const float* __restrict__ x, __half* __restrict__ xh,
                            const float* __restrict__ W1, __half* __restrict__ W1T,
                            const float* __restrict__ W2, __half* __restrict__ W2T,
                            const int* __restrict__ src, const int* __restrict__ dst,
                            int* __restrict__ cnt, int* __restrict__ slots) {
  int i = blockIdx.x * blockDim.x + threadIdx.x;
  if (i < PREP_X) {
    float4 v = reinterpret_cast<const float4*>(x)[i];
    reinterpret_cast<__half2*>(xh)[i * 2 + 0] = __floats2half2_rn(v.x, v.y);
    reinterpret_cast<__half2*>(xh)[i * 2 + 1] = __floats2half2_rn(v.z, v.w);
    return;
  }
  i -= PREP_X;
  if (i < PREP_W1) {
    int k = i / F1, n = i % F1;
    W1T[(size_t)n * IN_SIZE + k] = __float2half(W1[i]);
    return;
  }
  i -= PREP_W1;
  if (i < PREP_W2) {
    int k = i / F2, n = i % F2;
    W2T[(size_t)n * F1 + k] = __float2half(W2[i]);
    return;
  }
  i -= PREP_W2;
  if (i < N_EDGES) {
    int d = dst[i];
    int p = atomicAdd(&cnt[d], 1);
    if (p < SLOT_STRIDE) slots[d * SLOT_STRIDE + p] = src[i];
  }
}

// ---- shared LDS-staged MFMA GEMM tile (64 rows x 64 cols per block) ----
template <int KSTEPS>
__device__ __forceinline__ void gemm_tile(
    int rowBase, int colBase, const __half* __restrict__ A,
    const __half* __restrict__ BT, __half* __restrict__ Ch,
    const float* __restrict__ al, const float* __restrict__ ar,
    float* __restrict__ el, float* __restrict__ er,
    int M, int Ncols, int H, f16x8* Bs) {
  constexpr int K = KSTEPS * 32;
  constexpr int UPC = 4 * KSTEPS;  // 16B units per column
  int tid = threadIdx.x;
  for (int u = tid; u < 64 * UPC; u += 256) {
    int col = u / UPC;
    int off = u % UPC;
    f16x8 v = *reinterpret_cast<const f16x8*>(BT + (size_t)(colBase + col) * K + off * 8);
    Bs[u ^ (col & 7)] = v;
  }
  __syncthreads();
  int w = tid >> 6, lane = tid & 63;
  int r16 = lane & 15, ko = lane >> 4;
  int rb = rowBase + w * 16;
  int arow = rb + r16;
  if (arow >= M) arow = M - 1;
  const f16x8* Ap = reinterpret_cast<const f16x8*>(A + (size_t)arow * K + ko * 8);
  f32x4 acc[4] = {};
#pragma unroll
  for (int kk = 0; kk < KSTEPS; ++kk) {
    f16x8 af = Ap[kk * 4];
#pragma unroll
    for (int c = 0; c < 4; ++c) {
      int col = c * 16 + r16;
      f16x8 bf = Bs[(col * UPC + kk * 4 + ko) ^ (col & 7)];
      acc[c] = __builtin_amdgcn_mfma_f32_16x16x32_f16(af, bf, acc[c], 0, 0, 0);
    }
  }
  int h = colBase >> 6;
  float alv[4], arv[4];
#pragma unroll
  for (int c = 0; c < 4; ++c) {
    alv[c] = al[colBase + c * 16 + r16];
    arv[c] = ar[colBase + c * 16 + r16];
  }
#pragma unroll
  for (int r = 0; r < 4; ++r) {
    int row = rb + (lane >> 4) * 4 + r;
    bool ok = row < M;
    float pl = 0.f, pr = 0.f;
#pragma unroll
    for (int c = 0; c < 4; ++c) {
      float v = acc[c][r];
      if (ok) Ch[(size_t)row * Ncols + colBase + c * 16 + r16] = __float2half(v);
      pl += v * alv[c];
      pr += v * arv[c];
    }
#pragma unroll
    for (int o = 8; o > 0; o >>= 1) {
      pl += __shfl_xor(pl, o);
      pr += __shfl_xor(pr, o);
    }
    if (r16 == 0 && ok) {
      el[(size_t)row * H + h] = pl;
      er[(size_t)row * H + h] = pr;
    }
  }
}

template <int KSTEPS>
__global__ __launch_bounds__(256) void gemm_lds(
    const __half* __restrict__ A, const __half* __restrict__ BT,
    __half* __restrict__ Ch, const float* __restrict__ al,
    const float* __restrict__ ar, float* __restrict__ el,
    float* __restrict__ er, int M, int Ncols, int H) {
  __shared__ f16x8 Bs[64 * 4 * KSTEPS];
  gemm_tile<KSTEPS>(blockIdx.y * 64, blockIdx.x * 64,
                    A, BT, Ch, al, ar, el, er, M, Ncols, H, Bs);
}

__device__ __forceinline__ float leaky_exp(float v) {
  v = (v >= 0.f) ? v : 0.2f * v;
  return __expf(fminf(v, 80.f));
}

// ---- aggregation layer 1 (exp fused): block = node, wave = 128-ch tile ----
__global__ __launch_bounds__(256) void agg1_kernel(
    const int* __restrict__ cnt, const int* __restrict__ slots,
    const float* __restrict__ el, const float* __restrict__ er,
    const __half* __restrict__ fth, const float* __restrict__ bias,
    __half* __restrict__ out) {
  int t = threadIdx.x;
  int w = t >> 6, lane = t & 63;
  int n = blockIdx.x;
  int e = lane >> 4;
  int sub = lane & 15;
  int chb = w * 128 + sub * 8;
  int h = chb >> 6;
  int beg = n * SLOT_STRIDE;
  int end = beg + min(cnt[n], SLOT_STRIDE);
  float er_h = er[n * 8 + h];
  float s_run = 0.f;
  float acc[8] = {0.f, 0.f, 0.f, 0.f, 0.f, 0.f, 0.f, 0.f};
  if (beg < end) {
    int iA = min(beg + e, end - 1);
    bool okA = (beg + e) < end;
    int sA = slots[iA];
    int iB = min(beg + 4 + e, end - 1);
    bool okB = (beg + 4 + e) < end;
    int sB = slots[iB];
    float elA = el[sA * 8 + h];
    uint4 ftA = *reinterpret_cast<const uint4*>(fth + (size_t)sA * F1 + chb);
    for (int c = beg; c < end; c += 4) {
      int iC = min(c + 8 + e, end - 1);
      bool okC = (c + 8 + e) < end;
      int sC = slots[iC];
      float elB = el[sB * 8 + h];
      uint4 ftB = *reinterpret_cast<const uint4*>(fth + (size_t)sB * F1 + chb);
      float ex = okA ? leaky_exp(elA + er_h) : 0.f;
      float2 f0 = __half22float2(*reinterpret_cast<const __half2*>(&ftA.x));
      float2 f1 = __half22float2(*reinterpret_cast<const __half2*>(&ftA.y));
      float2 f2 = __half22float2(*reinterpret_cast<const __half2*>(&ftA.z));
      float2 f3 = __half22float2(*reinterpret_cast<const __half2*>(&ftA.w));
      acc[0] += ex * f0.x; acc[1] += ex * f0.y;
      acc[2] += ex * f1.x; acc[3] += ex * f1.y;
      acc[4] += ex * f2.x; acc[5] += ex * f2.y;
      acc[6] += ex * f3.x; acc[7] += ex * f3.y;
      s_run += ex;
      sA = sB; okA = okB; elA = elB; ftA = ftB;
      sB = sC; okB = okC;
    }
  }
#pragma unroll
  for (int i = 0; i < 8; ++i) {
    acc[i] += __shfl_xor(acc[i], 16);
    acc[i] += __shfl_xor(acc[i], 32);
  }
  s_run += __shfl_xor(s_run, 16);
  s_run += __shfl_xor(s_run, 32);
  if (e == 0) {
    float inv = (s_run > 0.f) ? (1.f / s_run) : 0.f;
    uint4 pack;
    __half2* ph = reinterpret_cast<__half2*>(&pack);
#pragma unroll
    for (int i = 0; i < 4; ++i) {
      float v0 = acc[2 * i + 0] * inv + bias[chb + 2 * i + 0];
      float v1 = acc[2 * i + 1] * inv + bias[chb + 2 * i + 1];
      v0 = (v0 > 0.f) ? v0 : (__expf(v0) - 1.f);  // ELU
      v1 = (v1 > 0.f) ? v1 : (__expf(v1) - 1.f);
      ph[i] = __floats2half2_rn(v0, v1);
    }
    *reinterpret_cast<uint4*>(out + (size_t)n * F1 + chb) = pack;
  }
}

// ---- aggregation layer 2 (H=1, exp fused): wave per node ----
template <int NPB>
__global__ __launch_bounds__(NPB * 64) void agg2_kernel(
    const int* __restrict__ cnt, const int* __restrict__ slots,
    const float* __restrict__ el, const float* __restrict__ er,
    const __half* __restrict__ fth, const float* __restrict__ bias,
    float* __restrict__ out) {
  int t = threadIdx.x;
  int w = t >> 6, lane = t & 63;
  int n = blockIdx.x * NPB + w;
  int e = lane >> 3;
  int q = lane & 7;
  int chb = q * 8;
  int beg = n * SLOT_STRIDE;
  int end = beg + min(cnt[n], SLOT_STRIDE);
  float er_n = er[n];
  float s_run = 0.f;
  float acc[8] = {0.f, 0.f, 0.f, 0.f, 0.f, 0.f, 0.f, 0.f};
  if (beg < end) {
    int iA = min(beg + e, end - 1);
    bool okA = (beg + e) < end;
    int sA = slots[iA];
    int iB = min(beg + 8 + e, end - 1);
    bool okB = (beg + 8 + e) < end;
    int sB = slots[iB];
    float elA = el[sA];
    uint4 ftA = *reinterpret_cast<const uint4*>(fth + (size_t)sA * F2 + chb);
    for (int c = beg; c < end; c += 8) {
      int iC = min(c + 16 + e, end - 1);
      bool okC = (c + 16 + e) < end;
      int sC = slots[iC];
      float elB = el[sB];
      uint4 ftB = *reinterpret_cast<const uint4*>(fth + (size_t)sB * F2 + chb);
      float ex = okA ? leaky_exp(elA + er_n) : 0.f;
      float2 f0 = __half22float2(*reinterpret_cast<const __half2*>(&ftA.x));
      float2 f1 = __half22float2(*reinterpret_cast<const __half2*>(&ftA.y));
      float2 f2 = __half22float2(*reinterpret_cast<const __half2*>(&ftA.z));
      float2 f3 = __half22float2(*reinterpret_cast<const __half2*>(&ftA.w));
      acc[0] += ex * f0.x; acc[1] += ex * f0.y;
      acc[2] += ex * f1.x; acc[3] += ex * f1.y;
      acc[4] += ex * f2.x; acc[5] += ex * f2.y;
      acc[6] += ex * f3.x; acc[7] += ex * f3.y;
      s_run += ex;
      sA = sB; okA = okB; elA = elB; ftA = ftB;
      sB = sC; okB = okC;
    }
  }
#pragma unroll
  for (int i = 0; i < 8; ++i) {
    acc[i] += __shfl_xor(acc[i], 8);
    acc[i] += __shfl_xor(acc[i], 16);
    acc[i] += __shfl_xor(acc[i], 32);
  }
  s_run += __shfl_xor(s_run, 8);
  s_run += __shfl_xor(s_run, 16);
  s_run += __shfl_xor(s_run, 32);
  if (e == 0) {
    float inv = (s_run > 0.f) ? (1.f / s_run) : 0.f;
    float o[8];
#pragma unroll
    for (int i = 0; i < 8; ++i) o[i] = acc[i] * inv + bias[chb + i];
    float* op = &out[(size_t)n * F2 + chb];
    *reinterpret_cast<float4*>(op) = make_float4(o[0], o[1], o[2], o[3]);
    *reinterpret_cast<float4*>(op + 4) = make_float4(o[4], o[5], o[6], o[7]);
  }
}

extern "C" void kernel_launch(void* const* d_in, const int* in_sizes, int n_in,
                              void* d_out, int out_size, void* d_ws, size_t ws_size,
                              hipStream_t stream) {
  const float* x   = (const float*)d_in[0];
  const int*   src = (const int*)d_in[1];
  const int*   dst = (const int*)d_in[2];
  const float* W1  = (const float*)d_in[3];
  const float* al1 = (const float*)d_in[4];
  const float* ar1 = (const float*)d_in[5];
  const float* b1  = (const float*)d_in[6];
  const float* W2  = (const float*)d_in[7];
  const float* al2 = (const float*)d_in[8];
  const float* ar2 = (const float*)d_in[9];
  const float* b2  = (const float*)d_in[10];
  float* out = (float*)d_out;

  char* ws = (char*)d_ws;
  size_t off = 0;
  auto alloc = [&](size_t bytes) -> void* {
    void* p = ws + off;
    off += (bytes + 255) & ~(size_t)255;
    return p;
  };
  size_t zbeg = off;
  int* cnt = (int*)alloc((size_t)N_NODES * 4);
  size_t zend = off;
  int* slots = (int*)alloc((size_t)N_NODES * SLOT_STRIDE * 4);
  __half* xh   = (__half*)alloc((size_t)N_NODES * IN_SIZE * 2);
  __half* W1T  = (__half*)alloc((size_t)IN_SIZE * F1 * 2);
  __half* W2T  = (__half*)alloc((size_t)F1 * F2 * 2);
  __half* ft1h = (__half*)alloc((size_t)N_NODES * F1 * 2);
  __half* h1h  = (__half*)alloc((size_t)N_NODES * F1 * 2);
  __half* ft2h = (__half*)alloc((size_t)N_NODES * F2 * 2);
  float* el1 = (float*)alloc((size_t)N_NODES * H1 * 4);
  float* er1 = (float*)alloc((size_t)N_NODES * H1 * 4);
  float* el2 = (float*)alloc((size_t)N_NODES * 4);
  float* er2 = (float*)alloc((size_t)N_NODES * 4);
  (void)ws_size; (void)in_sizes; (void)n_in; (void)out_size;

  hipMemsetAsync(ws + zbeg, 0, zend - zbeg, stream);

  dim3 b256(256);
  int prep_total = PREP_X + PREP_W1 + PREP_W2 + N_EDGES;

  // 1 dispatch: conversions + direct padded-bucket CSR scatter
  prep_kernel<<<(prep_total + 255) / 256, b256, 0, stream>>>(
      x, xh, W1, W1T, W2, W2T, src, dst, cnt, slots);

  // ---- layer 1 ----
  gemm_lds<IN_SIZE / 32><<<dim3(F1 / 64, (N_NODES + 63) / 64), b256, 0, stream>>>(
      xh, W1T, ft1h, al1, ar1, el1, er1, N_NODES, F1, H1);
  agg1_kernel<<<N_NODES, b256, 0, stream>>>(
      cnt, slots, el1, er1, ft1h, b1, h1h);

  // ---- layer 2 ----
  gemm_lds<F1 / 32><<<dim3(F2 / 64, (N_NODES + 63) / 64), b256, 0, stream>>>(
      h1h, W2T, ft2h, al2, ar2, el2, er2, N_NODES, F2, H2);
  agg2_kernel<4><<<N_NODES / 4, b256, 0, stream>>>(
      cnt, slots, el2, er2, ft2h, b2, out);
}

// Round 18
// 108.793 us; speedup vs baseline: 1.4673x; 1.0049x over previous
//
#include <hip/hip_runtime.h>
#include <hip/hip_bf16.h>
#include <hip/hip_fp16.h>
#include <math.h>

#define N_NODES 10000
#define N_EDGES 320000
#define IN_SIZE 256
#define H1 8
#define D1 64
#define F1 512
#define H2 1
#define D2 64
#define F2 64
#define SLOT_STRIDE 128   // padded per-node edge bucket; P(deg>128) ~ e^-32

using f16x8 = __attribute__((ext_vector_type(8))) _Float16;
using f32x4 = __attribute__((ext_vector_type(4))) float;

// ---- fused prep: x->f16, W1^T->f16, W2^T->f16, AND direct CSR-bucket scatter ----
#define PREP_X (N_NODES * IN_SIZE / 4)
#define PREP_W1 (IN_SIZE * F1)
#define PREP_W2 (F1 * F2)
__global__ void prep_kernel(const float* __restrict__ x, __half* __restrict__ xh,
                            const float* __restrict__ W1, __half* __restrict__ W1T,
                            const float* __restrict__ W2, __half* __restrict__ W2T,
                            const int* __restrict__ src, const int* __restrict__ dst,
                            int* __restrict__ cnt, int* __restrict__ slots) {
  int i = blockIdx.x * blockDim.x + threadIdx.x;
  if (i < PREP_X) {
    float4 v = reinterpret_cast<const float4*>(x)[i];
    reinterpret_cast<__half2*>(xh)[i * 2 + 0] = __floats2half2_rn(v.x, v.y);
    reinterpret_cast<__half2*>(xh)[i * 2 + 1] = __floats2half2_rn(v.z, v.w);
    return;
  }
  i -= PREP_X;
  if (i < PREP_W1) {
    int k = i / F1, n = i % F1;
    W1T[(size_t)n * IN_SIZE + k] = __float2half(W1[i]);
    return;
  }
  i -= PREP_W1;
  if (i < PREP_W2) {
    int k = i / F2, n = i % F2;
    W2T[(size_t)n * F1 + k] = __float2half(W2[i]);
    return;
  }
  i -= PREP_W2;
  if (i < N_EDGES) {
    int d = dst[i];
    int p = atomicAdd(&cnt[d], 1);
    if (p < SLOT_STRIDE) slots[d * SLOT_STRIDE + p] = src[i];
  }
}

// ---- shared LDS-staged MFMA GEMM tile (64 rows x 64 cols per block) ----
template <int KSTEPS>
__device__ __forceinline__ void gemm_tile(
    int rowBase, int colBase, const __half* __restrict__ A,
    const __half* __restrict__ BT, __half* __restrict__ Ch,
    const float* __restrict__ al, const float* __restrict__ ar,
    float* __restrict__ el, float* __restrict__ er,
    int M, int Ncols, int H, f16x8* Bs) {
  constexpr int K = KSTEPS * 32;
  constexpr int UPC = 4 * KSTEPS;  // 16B units per column
  int tid = threadIdx.x;
  for (int u = tid; u < 64 * UPC; u += 256) {
    int col = u / UPC;
    int off = u % UPC;
    f16x8 v = *reinterpret_cast<const f16x8*>(BT + (size_t)(colBase + col) * K + off * 8);
    Bs[u ^ (col & 7)] = v;
  }
  __syncthreads();
  int w = tid >> 6, lane = tid & 63;
  int r16 = lane & 15, ko = lane >> 4;
  int rb = rowBase + w * 16;
  int arow = rb + r16;
  if (arow >= M) arow = M - 1;
  const f16x8* Ap = reinterpret_cast<const f16x8*>(A + (size_t)arow * K + ko * 8);
  f32x4 acc[4] = {};
#pragma unroll
  for (int kk = 0; kk < KSTEPS; ++kk) {
    f16x8 af = Ap[kk * 4];
#pragma unroll
    for (int c = 0; c < 4; ++c) {
      int col = c * 16 + r16;
      f16x8 bf = Bs[(col * UPC + kk * 4 + ko) ^ (col & 7)];
      acc[c] = __builtin_amdgcn_mfma_f32_16x16x32_f16(af, bf, acc[c], 0, 0, 0);
    }
  }
  int h = colBase >> 6;
  float alv[4], arv[4];
#pragma unroll
  for (int c = 0; c < 4; ++c) {
    alv[c] = al[colBase + c * 16 + r16];
    arv[c] = ar[colBase + c * 16 + r16];
  }
#pragma unroll
  for (int r = 0; r < 4; ++r) {
    int row = rb + (lane >> 4) * 4 + r;
    bool ok = row < M;
    float pl = 0.f, pr = 0.f;
#pragma unroll
    for (int c = 0; c < 4; ++c) {
      float v = acc[c][r];
      if (ok) Ch[(size_t)row * Ncols + colBase + c * 16 + r16] = __float2half(v);
      pl += v * alv[c];
      pr += v * arv[c];
    }
#pragma unroll
    for (int o = 8; o > 0; o >>= 1) {
      pl += __shfl_xor(pl, o);
      pr += __shfl_xor(pr, o);
    }
    if (r16 == 0 && ok) {
      el[(size_t)row * H + h] = pl;
      er[(size_t)row * H + h] = pr;
    }
  }
}

template <int KSTEPS>
__global__ __launch_bounds__(256) void gemm_lds(
    const __half* __restrict__ A, const __half* __restrict__ BT,
    __half* __restrict__ Ch, const float* __restrict__ al,
    const float* __restrict__ ar, float* __restrict__ el,
    float* __restrict__ er, int M, int Ncols, int H) {
  __shared__ f16x8 Bs[64 * 4 * KSTEPS];
  gemm_tile<KSTEPS>(blockIdx.y * 64, blockIdx.x * 64,
                    A, BT, Ch, al, ar, el, er, M, Ncols, H, Bs);
}

__device__ __forceinline__ float leaky_exp(float v) {
  v = (v >= 0.f) ? v : 0.2f * v;
  return __expf(fminf(v, 80.f));
}

// ---- aggregation layer 1 (exp fused): block = node, wave = 128-ch tile ----
__global__ __launch_bounds__(256) void agg1_kernel(
    const int* __restrict__ cnt, const int* __restrict__ slots,
    const float* __restrict__ el, const float* __restrict__ er,
    const __half* __restrict__ fth, const float* __restrict__ bias,
    __half* __restrict__ out) {
  int t = threadIdx.x;
  int w = t >> 6, lane = t & 63;
  int n = blockIdx.x;
  int e = lane >> 4;
  int sub = lane & 15;
  int chb = w * 128 + sub * 8;
  int h = chb >> 6;
  int beg = n * SLOT_STRIDE;
  int end = beg + min(cnt[n], SLOT_STRIDE);
  float er_h = er[n * 8 + h];
  float s_run = 0.f;
  float acc[8] = {0.f, 0.f, 0.f, 0.f, 0.f, 0.f, 0.f, 0.f};
  if (beg < end) {
    int iA = min(beg + e, end - 1);
    bool okA = (beg + e) < end;
    int sA = slots[iA];
    int iB = min(beg + 4 + e, end - 1);
    bool okB = (beg + 4 + e) < end;
    int sB = slots[iB];
    float elA = el[sA * 8 + h];
    uint4 ftA = *reinterpret_cast<const uint4*>(fth + (size_t)sA * F1 + chb);
    for (int c = beg; c < end; c += 4) {
      int iC = min(c + 8 + e, end - 1);
      bool okC = (c + 8 + e) < end;
      int sC = slots[iC];
      float elB = el[sB * 8 + h];
      uint4 ftB = *reinterpret_cast<const uint4*>(fth + (size_t)sB * F1 + chb);
      float ex = okA ? leaky_exp(elA + er_h) : 0.f;
      float2 f0 = __half22float2(*reinterpret_cast<const __half2*>(&ftA.x));
      float2 f1 = __half22float2(*reinterpret_cast<const __half2*>(&ftA.y));
      float2 f2 = __half22float2(*reinterpret_cast<const __half2*>(&ftA.z));
      float2 f3 = __half22float2(*reinterpret_cast<const __half2*>(&ftA.w));
      acc[0] += ex * f0.x; acc[1] += ex * f0.y;
      acc[2] += ex * f1.x; acc[3] += ex * f1.y;
      acc[4] += ex * f2.x; acc[5] += ex * f2.y;
      acc[6] += ex * f3.x; acc[7] += ex * f3.y;
      s_run += ex;
      sA = sB; okA = okB; elA = elB; ftA = ftB;
      sB = sC; okB = okC;
    }
  }
#pragma unroll
  for (int i = 0; i < 8; ++i) {
    acc[i] += __shfl_xor(acc[i], 16);
    acc[i] += __shfl_xor(acc[i], 32);
  }
  s_run += __shfl_xor(s_run, 16);
  s_run += __shfl_xor(s_run, 32);
  if (e == 0) {
    float inv = (s_run > 0.f) ? (1.f / s_run) : 0.f;
    uint4 pack;
    __half2* ph = reinterpret_cast<__half2*>(&pack);
#pragma unroll
    for (int i = 0; i < 4; ++i) {
      float v0 = acc[2 * i + 0] * inv + bias[chb + 2 * i + 0];
      float v1 = acc[2 * i + 1] * inv + bias[chb + 2 * i + 1];
      v0 = (v0 > 0.f) ? v0 : (__expf(v0) - 1.f);  // ELU
      v1 = (v1 > 0.f) ? v1 : (__expf(v1) - 1.f);
      ph[i] = __floats2half2_rn(v0, v1);
    }
    *reinterpret_cast<uint4*>(out + (size_t)n * F1 + chb) = pack;
  }
}

// ---- aggregation layer 2 (H=1, exp fused): wave per node ----
template <int NPB>
__global__ __launch_bounds__(NPB * 64) void agg2_kernel(
    const int* __restrict__ cnt, const int* __restrict__ slots,
    const float* __restrict__ el, const float* __restrict__ er,
    const __half* __restrict__ fth, const float* __restrict__ bias,
    float* __restrict__ out) {
  int t = threadIdx.x;
  int w = t >> 6, lane = t & 63;
  int n = blockIdx.x * NPB + w;
  int e = lane >> 3;
  int q = lane & 7;
  int chb = q * 8;
  int beg = n * SLOT_STRIDE;
  int end = beg + min(cnt[n], SLOT_STRIDE);
  float er_n = er[n];
  float s_run = 0.f;
  float acc[8] = {0.f, 0.f, 0.f, 0.f, 0.f, 0.f, 0.f, 0.f};
  if (beg < end) {
    int iA = min(beg + e, end - 1);
    bool okA = (beg + e) < end;
    int sA = slots[iA];
    int iB = min(beg + 8 + e, end - 1);
    bool okB = (beg + 8 + e) < end;
    int sB = slots[iB];
    float elA = el[sA];
    uint4 ftA = *reinterpret_cast<const uint4*>(fth + (size_t)sA * F2 + chb);
    for (int c = beg; c < end; c += 8) {
      int iC = min(c + 16 + e, end - 1);
      bool okC = (c + 16 + e) < end;
      int sC = slots[iC];
      float elB = el[sB];
      uint4 ftB = *reinterpret_cast<const uint4*>(fth + (size_t)sB * F2 + chb);
      float ex = okA ? leaky_exp(elA + er_n) : 0.f;
      float2 f0 = __half22float2(*reinterpret_cast<const __half2*>(&ftA.x));
      float2 f1 = __half22float2(*reinterpret_cast<const __half2*>(&ftA.y));
      float2 f2 = __half22float2(*reinterpret_cast<const __half2*>(&ftA.z));
      float2 f3 = __half22float2(*reinterpret_cast<const __half2*>(&ftA.w));
      acc[0] += ex * f0.x; acc[1] += ex * f0.y;
      acc[2] += ex * f1.x; acc[3] += ex * f1.y;
      acc[4] += ex * f2.x; acc[5] += ex * f2.y;
      acc[6] += ex * f3.x; acc[7] += ex * f3.y;
      s_run += ex;
      sA = sB; okA = okB; elA = elB; ftA = ftB;
      sB = sC; okB = okC;
    }
  }
#pragma unroll
  for (int i = 0; i < 8; ++i) {
    acc[i] += __shfl_xor(acc[i], 8);
    acc[i] += __shfl_xor(acc[i], 16);
    acc[i] += __shfl_xor(acc[i], 32);
  }
  s_run += __shfl_xor(s_run, 8);
  s_run += __shfl_xor(s_run, 16);
  s_run += __shfl_xor(s_run, 32);
  if (e == 0) {
    float inv = (s_run > 0.f) ? (1.f / s_run) : 0.f;
    float o[8];
#pragma unroll
    for (int i = 0; i < 8; ++i) o[i] = acc[i] * inv + bias[chb + i];
    float* op = &out[(size_t)n * F2 + chb];
    *reinterpret_cast<float4*>(op) = make_float4(o[0], o[1], o[2], o[3]);
    *reinterpret_cast<float4*>(op + 4) = make_float4(o[4], o[5], o[6], o[7]);
  }
}

extern "C" void kernel_launch(void* const* d_in, const int* in_sizes, int n_in,
                              void* d_out, int out_size, void* d_ws, size_t ws_size,
                              hipStream_t stream) {
  const float* x   = (const float*)d_in[0];
  const int*   src = (const int*)d_in[1];
  const int*   dst = (const int*)d_in[2];
  const float* W1  = (const float*)d_in[3];
  const float* al1 = (const float*)d_in[4];
  const float* ar1 = (const float*)d_in[5];
  const float* b1  = (const float*)d_in[6];
  const float* W2  = (const float*)d_in[7];
  const float* al2 = (const float*)d_in[8];
  const float* ar2 = (const float*)d_in[9];
  const float* b2  = (const float*)d_in[10];
  float* out = (float*)d_out;

  char* ws = (char*)d_ws;
  size_t off = 0;
  auto alloc = [&](size_t bytes) -> void* {
    void* p = ws + off;
    off += (bytes + 255) & ~(size_t)255;
    return p;
  };
  size_t zbeg = off;
  int* cnt = (int*)alloc((size_t)N_NODES * 4);
  size_t zend = off;
  int* slots = (int*)alloc((size_t)N_NODES * SLOT_STRIDE * 4);
  __half* xh   = (__half*)alloc((size_t)N_NODES * IN_SIZE * 2);
  __half* W1T  = (__half*)alloc((size_t)IN_SIZE * F1 * 2);
  __half* W2T  = (__half*)alloc((size_t)F1 * F2 * 2);
  __half* ft1h = (__half*)alloc((size_t)N_NODES * F1 * 2);
  __half* h1h  = (__half*)alloc((size_t)N_NODES * F1 * 2);
  __half* ft2h = (__half*)alloc((size_t)N_NODES * F2 * 2);
  float* el1 = (float*)alloc((size_t)N_NODES * H1 * 4);
  float* er1 = (float*)alloc((size_t)N_NODES * H1 * 4);
  float* el2 = (float*)alloc((size_t)N_NODES * 4);
  float* er2 = (float*)alloc((size_t)N_NODES * 4);
  (void)ws_size; (void)in_sizes; (void)n_in; (void)out_size;

  hipMemsetAsync(ws + zbeg, 0, zend - zbeg, stream);

  dim3 b256(256);
  int prep_total = PREP_X + PREP_W1 + PREP_W2 + N_EDGES;

  // 1 dispatch: conversions + direct padded-bucket CSR scatter
  prep_kernel<<<(prep_total + 255) / 256, b256, 0, stream>>>(
      x, xh, W1, W1T, W2, W2T, src, dst, cnt, slots);

  // ---- layer 1 ----
  gemm_lds<IN_SIZE / 32><<<dim3(F1 / 64, (N_NODES + 63) / 64), b256, 0, stream>>>(
      xh, W1T, ft1h, al1, ar1, el1, er1, N_NODES, F1, H1);
  agg1_kernel<<<N_NODES, b256, 0, stream>>>(
      cnt, slots, el1, er1, ft1h, b1, h1h);

  // ---- layer 2 ----
  gemm_lds<F1 / 32><<<dim3(F2 / 64, (N_NODES + 63) / 64), b256, 0, stream>>>(
      h1h, W2T, ft2h, al2, ar2, el2, er2, N_NODES, F2, H2);
  agg2_kernel<4><<<N_NODES / 4, b256, 0, stream>>>(
      cnt, slots, el2, er2, ft2h, b2, out);
}